// Round 25
// baseline (120.644 us; speedup 1.0000x reference)
//
#include <hip/hip_runtime.h>
#include <hip/hip_bf16.h>
#include <math.h>

#define N_ROWS 8192
#define DIM 1024
#define DIMB 1024         // bytes per int8 row
#define BM 256
#define BN 256
#define BKB 128           // K-tile in BYTES (=128 int8 elems = 2 MFMA k-steps)
#define NT (DIMB / BKB)   // 8 K-tiles

typedef __attribute__((ext_vector_type(4))) int i32x4;

__device__ __forceinline__ unsigned pk4(float4 v, float f) {
    float c0 = fmaxf(-127.f, fminf(127.f, v.x * f));
    float c1 = fmaxf(-127.f, fminf(127.f, v.y * f));
    float c2 = fmaxf(-127.f, fminf(127.f, v.z * f));
    float c3 = fmaxf(-127.f, fminf(127.f, v.w * f));
    int b0 = (int)rintf(c0), b1 = (int)rintf(c1);
    int b2 = (int)rintf(c2), b3 = (int)rintf(c3);
    return (unsigned)(b0 & 0xFF) | ((unsigned)(b1 & 0xFF) << 8) |
           ((unsigned)(b2 & 0xFF) << 16) | ((unsigned)(b3 & 0xFF) << 24);
}

// ---------------- Kernel 1: row L2-normalize fp32 -> per-row-scaled int8 ----------------
__global__ __launch_bounds__(256) void cl_norm_kernel(
    const float* __restrict__ z, signed char* __restrict__ zq, float* __restrict__ qs) {
    const int row  = blockIdx.x * 4 + (threadIdx.x >> 6);
    const int lane = threadIdx.x & 63;
    const float* zr = z + (size_t)row * DIM + lane * 16;
    float4 v[4];
    float ss = 0.f, am = 0.f;
#pragma unroll
    for (int j = 0; j < 4; ++j) {
        v[j] = *reinterpret_cast<const float4*>(zr + j * 4);
        ss += v[j].x * v[j].x + v[j].y * v[j].y + v[j].z * v[j].z + v[j].w * v[j].w;
        am = fmaxf(am, fmaxf(fmaxf(fabsf(v[j].x), fabsf(v[j].y)),
                             fmaxf(fabsf(v[j].z), fabsf(v[j].w))));
    }
#pragma unroll
    for (int m = 1; m < 64; m <<= 1) {
        ss += __shfl_xor(ss, m, 64);
        am = fmaxf(am, __shfl_xor(am, m, 64));
    }
    const float scale = 1.0f / fmaxf(sqrtf(ss), 1e-8f);
    const float amax  = am * scale;
    if (lane == 0) qs[row] = amax * (1.0f / 127.0f);
    const float f = (amax > 0.f) ? scale * (127.0f / amax) : 0.f;
    uint4 o;
    o.x = pk4(v[0], f);
    o.y = pk4(v[1], f);
    o.z = pk4(v[2], f);
    o.w = pk4(v[3], f);
    *reinterpret_cast<uint4*>(zq + (size_t)row * DIMB + lane * 16) = o;
}

// ---------------- Kernel 2: symmetric triangle int8 GEMM + dual partial LSE ----------------
// Best-proven structure (120.5us total): 2-phase K-loop with explicit lgkm drains,
// counted vmcnt(6) boundary, strips-first block ordering.
// blocks 0..63   = 64 column strips (256x64) of the last 16 triangle tiles,
// blocks 64..575 = 512 full 256x256 tiles.
__device__ __forceinline__ void stage_round(
    const signed char* __restrict__ zq, int g_row0, int k0,
    char* lds_round_base, int t) {
    const int r  = t >> 3;             // row within round (0..63)
    const int ch = (t & 7) ^ (r & 7);  // pre-swizzled 16B chunk (rule #21)
    const signed char* src = zq + (size_t)(g_row0 + r) * DIMB + k0 + ch * 16;
    __builtin_amdgcn_global_load_lds(
        (const __attribute__((address_space(1))) void*)src,
        (__attribute__((address_space(3))) void*)(lds_round_base + t * 16), 16, 0, 0);
}

__device__ __forceinline__ i32x4 ld_frag(const char* tile, int row, int kbyte, int xm) {
    return *reinterpret_cast<const i32x4*>(tile + row * 128 + (kbyte ^ xm));
}

#define MFMAI8(a, b, c) __builtin_amdgcn_mfma_i32_16x16x64_i8((a), (b), (c), 0, 0, 0)

// Half-row of quadrants: MH fixed, both NH: 4(mi) x 4(nf) x 2(k) = 32 MFMAs
template <int MH>
__device__ __forceinline__ void mfma_half(i32x4 (&acc)[8][4], const i32x4 (&af)[4][2],
                                          const i32x4 (&bf)[4][2]) {
#pragma unroll
    for (int mi = 0; mi < 4; ++mi)
#pragma unroll
        for (int nf = 0; nf < 4; ++nf)
#pragma unroll
            for (int k = 0; k < 2; ++k)
                acc[MH * 4 + mi][nf] = MFMAI8(af[mi][k], bf[nf][k], acc[MH * 4 + mi][nf]);
}

__global__ __launch_bounds__(512, 2) void cl_simlse8_kernel(
    const signed char* __restrict__ zq, const float* __restrict__ qs,
    float2* __restrict__ part,  // [128 chunks][8192 rows]
    float* __restrict__ pos) {  // [8192]
    extern __shared__ char smem[];  // 128 KB

    const int t    = threadIdx.x;
    const int lane = t & 63;
    const int wid  = t >> 6;   // 0..7
    const int l15  = lane & 15;
    const int xm   = (lane & 7) << 4;        // read-side swizzle mask ((row&7)<<4)
    const int kq16 = ((lane >> 4) & 3) * 16; // k sub-chunk byte offset
    const float invT = 1.0f / 0.07f;

    if (blockIdx.x >= 64) {
        // ================= FULL 256x256 tile path (triangle ids 0..511) =================
        const int wr = wid >> 2;  // 0..1 (M)
        const int wc = wid & 3;   // 0..3 (N)
        const int fb = blockIdx.x - 64;
        const int id2 = (fb & 7) * 64 + (fb >> 3);  // bijective XCD chunking
        int ri = 0, rem = id2;
        while (rem >= 32 - ri) { rem -= 32 - ri; ++ri; }
        const int ci = ri + rem;  // ri <= ci
        const int rbase = ri * BM;
        const int cbase = ci * BN;

        const i32x4 zero4 = {0, 0, 0, 0};
        i32x4 acc[8][4];
#pragma unroll
        for (int m = 0; m < 8; ++m)
#pragma unroll
            for (int n = 0; n < 4; ++n) acc[m][n] = zero4;

        i32x4 af[4][2];   // current A-half (overwritten between phases)
        i32x4 bf[4][2];   // all B (nh0+nh1)

        // ---- prologue: stage kt0 (8 rounds) + kt1 A0+B (6 rounds) ----
        {
            char* A0b = smem;
            char* B0b = smem + 32768;
            char* A1b = smem + 65536;
            char* B1b = smem + 98304;
            stage_round(zq, rbase + 0,   0, A0b + 0,     t);
            stage_round(zq, rbase + 64,  0, A0b + 8192,  t);
            stage_round(zq, rbase + 128, 0, A0b + 16384, t);
            stage_round(zq, rbase + 192, 0, A0b + 24576, t);
            stage_round(zq, cbase + 0,   0, B0b + 0,     t);
            stage_round(zq, cbase + 64,  0, B0b + 8192,  t);
            stage_round(zq, cbase + 128, 0, B0b + 16384, t);
            stage_round(zq, cbase + 192, 0, B0b + 24576, t);
            stage_round(zq, rbase + 0,   BKB, A1b + 0,     t);
            stage_round(zq, rbase + 64,  BKB, A1b + 8192,  t);
            stage_round(zq, cbase + 0,   BKB, B1b + 0,     t);
            stage_round(zq, cbase + 64,  BKB, B1b + 8192,  t);
            stage_round(zq, cbase + 128, BKB, B1b + 16384, t);
            stage_round(zq, cbase + 192, BKB, B1b + 24576, t);
            asm volatile("s_waitcnt vmcnt(6)" ::: "memory");  // kt0 landed; kt1 A0+B in flight
            __builtin_amdgcn_sched_barrier(0);
            __builtin_amdgcn_s_barrier();
        }

        // ---- main loop: 2 phases per K-tile ----
        for (int kt = 0; kt < NT; ++kt) {
            const int c = kt & 1;
            char* curA = smem + c * 65536;
            char* curB = curA + 32768;
            char* nxtA = smem + (c ^ 1) * 65536;
            const int k2 = (kt + 2) * BKB;

            // ---- phase A: read A-mh0 (8) + B both halves (8); stage A1(kt+1); MFMA mh0 ----
#pragma unroll
            for (int mi = 0; mi < 4; ++mi)
#pragma unroll
                for (int k = 0; k < 2; ++k)
                    af[mi][k] = ld_frag(curA, wr * 64 + mi * 16 + l15, k * 64 + kq16, xm);
#pragma unroll
            for (int nf = 0; nf < 4; ++nf)
#pragma unroll
                for (int k = 0; k < 2; ++k)
                    bf[nf][k] = ld_frag(curB, wc * 64 + (nf >> 1) * 32 + (nf & 1) * 16 + l15,
                                        k * 64 + kq16, xm);
            if (kt + 1 < NT) {  // A1(kt+1) into nxt (its region last read in kt-1 phB, done)
                stage_round(zq, rbase + 128, (kt + 1) * BKB, nxtA + 16384, t);
                stage_round(zq, rbase + 192, (kt + 1) * BKB, nxtA + 24576, t);
            }
            __builtin_amdgcn_s_barrier();
            asm volatile("s_waitcnt lgkmcnt(0)" ::: "memory");
            __builtin_amdgcn_sched_barrier(0);
            __builtin_amdgcn_s_setprio(1);
            mfma_half<0>(acc, af, bf);
            __builtin_amdgcn_s_setprio(0);
            __builtin_amdgcn_s_barrier();

            // ---- phase B: read A-mh1 (8, overwrite af); stage A0+B(kt+2); MFMA mh1; boundary ----
#pragma unroll
            for (int mi = 0; mi < 4; ++mi)
#pragma unroll
                for (int k = 0; k < 2; ++k)
                    af[mi][k] = ld_frag(curA, 128 + wr * 64 + mi * 16 + l15, k * 64 + kq16, xm);
            if (kt + 2 < NT) {  // curA0/curB reads completed at phase-A barrier
                stage_round(zq, rbase + 0,   k2, curA + 0,     t);
                stage_round(zq, rbase + 64,  k2, curA + 8192,  t);
                stage_round(zq, cbase + 0,   k2, curB + 0,     t);
                stage_round(zq, cbase + 64,  k2, curB + 8192,  t);
                stage_round(zq, cbase + 128, k2, curB + 16384, t);
                stage_round(zq, cbase + 192, k2, curB + 24576, t);
            }
            __builtin_amdgcn_s_barrier();
            asm volatile("s_waitcnt lgkmcnt(0)" ::: "memory");
            __builtin_amdgcn_sched_barrier(0);
            __builtin_amdgcn_s_setprio(1);
            mfma_half<1>(acc, af, bf);
            __builtin_amdgcn_s_setprio(0);
            if (kt < NT - 2) {
                asm volatile("s_waitcnt vmcnt(6)" ::: "memory");  // waits A1(kt+1), leaves own 6
                __builtin_amdgcn_sched_barrier(0);
            } else if (kt == NT - 2) {
                asm volatile("s_waitcnt vmcnt(0)" ::: "memory");  // drain tail
                __builtin_amdgcn_sched_barrier(0);
            }
            __builtin_amdgcn_s_barrier();
        }

        // ---- epilogue A: row partials (dequant: logit = acc * qs[r] * qs[c] / T) ----
        const int chunk = ci * 4 + wc;
        float qc[4];
#pragma unroll
        for (int nf = 0; nf < 4; ++nf)
            qc[nf] = qs[cbase + wc * 64 + (nf >> 1) * 32 + (nf & 1) * 16 + l15] * invT;
#pragma unroll
        for (int mh = 0; mh < 2; ++mh) {
#pragma unroll
            for (int mi = 0; mi < 4; ++mi) {
#pragma unroll
                for (int reg = 0; reg < 4; ++reg) {
                    const int grow = rbase + wr * 64 + mh * 128 + mi * 16 + (lane >> 4) * 4 + reg;
                    const int posj = (grow - 4096) & (N_ROWS - 1);
                    const float qr = qs[grow];
                    float vals[4];
                    float rmax = -3.4e38f;
#pragma unroll
                    for (int nf = 0; nf < 4; ++nf) {
                        const int gcol = cbase + wc * 64 + (nf >> 1) * 32 + (nf & 1) * 16 + l15;
                        float logit = (float)acc[mh * 4 + mi][nf][reg] * qr * qc[nf];
                        if (gcol == grow) logit = -9e15f * invT;  // diag mask
                        if (gcol == posj) {
                            pos[grow] = logit;   // involution: pair covered once, both sides
                            pos[gcol] = logit;
                        }
                        vals[nf] = logit;
                        rmax = fmaxf(rmax, logit);
                    }
#pragma unroll
                    for (int msk = 1; msk < 16; msk <<= 1)
                        rmax = fmaxf(rmax, __shfl_xor(rmax, msk, 64));
                    float s = 0.f;
#pragma unroll
                    for (int nf = 0; nf < 4; ++nf) s += __expf(vals[nf] - rmax);
#pragma unroll
                    for (int msk = 1; msk < 16; msk <<= 1) s += __shfl_xor(s, msk, 64);
                    if (l15 == 0) {
                        part[(size_t)chunk * N_ROWS + grow] = make_float2(rmax, s);
                    }
                }
            }
        }

        // ---- epilogue B: column partials (transpose rows) — off-diag only ----
        if (ri != ci) {
#pragma unroll
            for (int mh = 0; mh < 2; ++mh) {
                const int chunkT = ri * 4 + wr + mh * 2;
                float qrow[4][4];
#pragma unroll
                for (int mi = 0; mi < 4; ++mi)
#pragma unroll
                    for (int reg = 0; reg < 4; ++reg)
                        qrow[mi][reg] = qs[rbase + wr * 64 + mh * 128 + mi * 16 +
                                           (lane >> 4) * 4 + reg] * invT;
#pragma unroll
                for (int nf = 0; nf < 4; ++nf) {
                    const int gcol = cbase + wc * 64 + (nf >> 1) * 32 + (nf & 1) * 16 + l15;
                    const float qcg = qs[gcol];
                    float cmax = -3.4e38f;
#pragma unroll
                    for (int mi = 0; mi < 4; ++mi)
#pragma unroll
                        for (int reg = 0; reg < 4; ++reg)
                            cmax = fmaxf(cmax, (float)acc[mh * 4 + mi][nf][reg] *
                                                   qrow[mi][reg] * qcg);
                    cmax = fmaxf(cmax, __shfl_xor(cmax, 16, 64));
                    cmax = fmaxf(cmax, __shfl_xor(cmax, 32, 64));
                    float cs = 0.f;
#pragma unroll
                    for (int mi = 0; mi < 4; ++mi)
#pragma unroll
                        for (int reg = 0; reg < 4; ++reg)
                            cs += __expf((float)acc[mh * 4 + mi][nf][reg] *
                                             qrow[mi][reg] * qcg - cmax);
                    cs += __shfl_xor(cs, 16, 64);
                    cs += __shfl_xor(cs, 32, 64);
                    if (lane < 16) {
                        part[(size_t)chunkT * N_ROWS + gcol] = make_float2(cmax, cs);
                    }
                }
            }
        }
    } else {
        // ================= STRIP path: 256 rows x 64 cols (tiles 512..527, 4 strips) =================
        const int s     = blockIdx.x;          // 0..63, launched FIRST
        const int id2   = 512 + (s >> 2);
        const int strip = s & 3;
        int ri = 0, rem = id2;
        while (rem >= 32 - ri) { rem -= 32 - ri; ++ri; }
        const int ci = ri + rem;
        const int rbase = ri * BM;
        const int scol  = ci * BN + strip * 64;

        char* Ab0 = smem;
        char* Ab1 = smem + 32768;
        char* Bb0 = smem + 65536;
        char* Bb1 = smem + 65536 + 8192;
        float2* colm = (float2*)(smem + 98304);  // [8 waves][64 cols]

        const i32x4 zero4 = {0, 0, 0, 0};
        i32x4 acc2[2][4];
#pragma unroll
        for (int m = 0; m < 2; ++m)
#pragma unroll
            for (int n = 0; n < 4; ++n) acc2[m][n] = zero4;
        i32x4 a2[2][2], b2[4][2];

        stage_round(zq, rbase + 0,   0, Ab0 + 0,     t);
        stage_round(zq, rbase + 64,  0, Ab0 + 8192,  t);
        stage_round(zq, rbase + 128, 0, Ab0 + 16384, t);
        stage_round(zq, rbase + 192, 0, Ab0 + 24576, t);
        stage_round(zq, scol,        0, Bb0,         t);
        asm volatile("s_waitcnt vmcnt(0)" ::: "memory");
        __builtin_amdgcn_sched_barrier(0);
        __builtin_amdgcn_s_barrier();

        for (int kt = 0; kt < NT; ++kt) {
            char* curA = (kt & 1) ? Ab1 : Ab0;
            char* curB = (kt & 1) ? Bb1 : Bb0;
            char* nxtA = (kt & 1) ? Ab0 : Ab1;
            char* nxtB = (kt & 1) ? Bb0 : Bb1;
            if (kt + 1 < NT) {
                const int k1 = (kt + 1) * BKB;
                stage_round(zq, rbase + 0,   k1, nxtA + 0,     t);
                stage_round(zq, rbase + 64,  k1, nxtA + 8192,  t);
                stage_round(zq, rbase + 128, k1, nxtA + 16384, t);
                stage_round(zq, rbase + 192, k1, nxtA + 24576, t);
                stage_round(zq, scol,        k1, nxtB,         t);
            }
#pragma unroll
            for (int mi = 0; mi < 2; ++mi)
#pragma unroll
                for (int k = 0; k < 2; ++k)
                    a2[mi][k] = ld_frag(curA, wid * 32 + mi * 16 + l15, k * 64 + kq16, xm);
#pragma unroll
            for (int ni = 0; ni < 4; ++ni)
#pragma unroll
                for (int k = 0; k < 2; ++k)
                    b2[ni][k] = ld_frag(curB, ni * 16 + l15, k * 64 + kq16, xm);
            asm volatile("s_waitcnt lgkmcnt(0)" ::: "memory");
            __builtin_amdgcn_sched_barrier(0);
            __builtin_amdgcn_s_setprio(1);
#pragma unroll
            for (int mi = 0; mi < 2; ++mi)
#pragma unroll
                for (int ni = 0; ni < 4; ++ni)
#pragma unroll
                    for (int k = 0; k < 2; ++k)
                        acc2[mi][ni] = MFMAI8(a2[mi][k], b2[ni][k], acc2[mi][ni]);
            __builtin_amdgcn_s_setprio(0);
            asm volatile("s_waitcnt vmcnt(0)" ::: "memory");
            __builtin_amdgcn_sched_barrier(0);
            __builtin_amdgcn_s_barrier();
        }

        // ---- epilogue A: row partials ----
        const int chunk = scol >> 6;
        float qc[4];
#pragma unroll
        for (int ni = 0; ni < 4; ++ni) qc[ni] = qs[scol + ni * 16 + l15] * invT;
#pragma unroll
        for (int mi = 0; mi < 2; ++mi) {
#pragma unroll
            for (int reg = 0; reg < 4; ++reg) {
                const int grow = rbase + wid * 32 + mi * 16 + (lane >> 4) * 4 + reg;
                const int posj = (grow - 4096) & (N_ROWS - 1);
                const float qr = qs[grow];
                float vals[4];
                float rmax = -3.4e38f;
#pragma unroll
                for (int ni = 0; ni < 4; ++ni) {
                    const int gcol = scol + ni * 16 + l15;
                    float logit = (float)acc2[mi][ni][reg] * qr * qc[ni];
                    if (gcol == grow) logit = -9e15f * invT;
                    if (gcol == posj) {
                        pos[grow] = logit;
                        pos[gcol] = logit;
                    }
                    vals[ni] = logit;
                    rmax = fmaxf(rmax, logit);
                }
#pragma unroll
                for (int msk = 1; msk < 16; msk <<= 1)
                    rmax = fmaxf(rmax, __shfl_xor(rmax, msk, 64));
                float sum = 0.f;
#pragma unroll
                for (int ni = 0; ni < 4; ++ni) sum += __expf(vals[ni] - rmax);
#pragma unroll
                for (int msk = 1; msk < 16; msk <<= 1) sum += __shfl_xor(sum, msk, 64);
                if (l15 == 0) {
                    part[(size_t)chunk * N_ROWS + grow] = make_float2(rmax, sum);
                }
            }
        }

        // ---- epilogue B: column partials (wave pairs merge via LDS) ----
        if (ri != ci) {
            float qrow[2][4];
#pragma unroll
            for (int mi = 0; mi < 2; ++mi)
#pragma unroll
                for (int reg = 0; reg < 4; ++reg)
                    qrow[mi][reg] = qs[rbase + wid * 32 + mi * 16 + (lane >> 4) * 4 + reg] * invT;
#pragma unroll
            for (int ni = 0; ni < 4; ++ni) {
                const float qcg = qs[scol + ni * 16 + l15];
                float cmax = -3.4e38f;
#pragma unroll
                for (int mi = 0; mi < 2; ++mi)
#pragma unroll
                    for (int reg = 0; reg < 4; ++reg)
                        cmax = fmaxf(cmax, (float)acc2[mi][ni][reg] * qrow[mi][reg] * qcg);
                cmax = fmaxf(cmax, __shfl_xor(cmax, 16, 64));
                cmax = fmaxf(cmax, __shfl_xor(cmax, 32, 64));
                float cs = 0.f;
#pragma unroll
                for (int mi = 0; mi < 2; ++mi)
#pragma unroll
                    for (int reg = 0; reg < 4; ++reg)
                        cs += __expf((float)acc2[mi][ni][reg] * qrow[mi][reg] * qcg - cmax);
                cs += __shfl_xor(cs, 16, 64);
                cs += __shfl_xor(cs, 32, 64);
                if (lane < 16) {
                    colm[wid * 64 + ni * 16 + lane] = make_float2(cmax, cs);
                }
            }
            __syncthreads();
            if ((wid & 1) == 0) {
                const float2 p0 = colm[wid * 64 + lane];
                const float2 p1 = colm[(wid + 1) * 64 + lane];
                const float M = fmaxf(p0.x, p1.x);
                const float S = p0.y * __expf(p0.x - M) + p1.y * __expf(p1.x - M);
                const int chunkT = ri * 4 + (wid >> 1);
                part[(size_t)chunkT * N_ROWS + scol + lane] = make_float2(M, S);
            }
        }
    }
}

// ---------------- Kernel 3: combine partials -> per-block nll sums ----------------
__global__ __launch_bounds__(256) void cl_combine_kernel(
    const float2* __restrict__ part, const float* __restrict__ pos,
    float* __restrict__ bsum) {
    const int r = blockIdx.x * 256 + threadIdx.x;
    float M = -3.4e38f;
#pragma unroll 8
    for (int c = 0; c < 128; ++c) M = fmaxf(M, part[(size_t)c * N_ROWS + r].x);
    float L = 0.f;
#pragma unroll 8
    for (int c = 0; c < 128; ++c) {
        const float2 p = part[(size_t)c * N_ROWS + r];
        L += p.y * __expf(p.x - M);
    }
    float nll = M + logf(L) - pos[r];
    __shared__ float red[4];
#pragma unroll
    for (int msk = 1; msk < 64; msk <<= 1) nll += __shfl_xor(nll, msk, 64);
    if ((threadIdx.x & 63) == 0) red[threadIdx.x >> 6] = nll;
    __syncthreads();
    if (threadIdx.x == 0) bsum[blockIdx.x] = red[0] + red[1] + red[2] + red[3];
}

// ---------------- Kernel 4: final mean ----------------
__global__ void cl_final_kernel(const float* __restrict__ bsum, float* __restrict__ out) {
    const int lane = threadIdx.x;
    float v = (lane < 32) ? bsum[lane] : 0.f;
#pragma unroll
    for (int msk = 1; msk < 64; msk <<= 1) v += __shfl_xor(v, msk, 64);
    if (lane == 0) out[0] = v * (1.0f / (float)N_ROWS);
}

extern "C" void kernel_launch(void* const* d_in, const int* in_sizes, int n_in,
                              void* d_out, int out_size, void* d_ws, size_t ws_size,
                              hipStream_t stream) {
    const float* z = (const float*)d_in[0];
    float* out = (float*)d_out;

    uint8_t* ws = (uint8_t*)d_ws;
    signed char* zq = (signed char*)ws;                        //  8 MB
    float2* part = (float2*)(ws + ((size_t)8 << 20));          //  8 MB
    float* pos   = (float*)(ws + ((size_t)16 << 20));          // 32 KB
    float* qs    = (float*)(ws + ((size_t)16 << 20) + 32768);  // 32 KB
    float* bsum  = (float*)(ws + ((size_t)16 << 20) + 65536);  // 128 B

    (void)hipFuncSetAttribute((const void*)cl_simlse8_kernel,
                              hipFuncAttributeMaxDynamicSharedMemorySize, 131072);

    cl_norm_kernel<<<N_ROWS / 4, 256, 0, stream>>>(z, zq, qs);
    cl_simlse8_kernel<<<576, 512, 131072, stream>>>(zq, qs, part, pos);  // strips first
    cl_combine_kernel<<<N_ROWS / 256, 256, 0, stream>>>(part, pos, bsum);
    cl_final_kernel<<<1, 64, 0, stream>>>(bsum, out);
}

// Round 26
// 118.984 us; speedup vs baseline: 1.0140x; 1.0140x over previous
//
#include <hip/hip_runtime.h>
#include <hip/hip_bf16.h>
#include <math.h>

#define N_ROWS 8192
#define DIM 1024
#define DIMB 1024         // bytes per int8 row
#define BM 256
#define BN 256
#define BKB 128           // K-tile in BYTES (=128 int8 elems = 2 MFMA k-steps)
#define NT (DIMB / BKB)   // 8 K-tiles

typedef __attribute__((ext_vector_type(4))) int i32x4;

__device__ __forceinline__ unsigned pk4(float4 v, float f) {
    float c0 = fmaxf(-127.f, fminf(127.f, v.x * f));
    float c1 = fmaxf(-127.f, fminf(127.f, v.y * f));
    float c2 = fmaxf(-127.f, fminf(127.f, v.z * f));
    float c3 = fmaxf(-127.f, fminf(127.f, v.w * f));
    int b0 = (int)rintf(c0), b1 = (int)rintf(c1);
    int b2 = (int)rintf(c2), b3 = (int)rintf(c3);
    return (unsigned)(b0 & 0xFF) | ((unsigned)(b1 & 0xFF) << 8) |
           ((unsigned)(b2 & 0xFF) << 16) | ((unsigned)(b3 & 0xFF) << 24);
}

// ---------------- Kernel 1: row L2-normalize fp32 -> per-row-scaled int8 ----------------
__global__ __launch_bounds__(256) void cl_norm_kernel(
    const float* __restrict__ z, signed char* __restrict__ zq, float* __restrict__ qs) {
    const int row  = blockIdx.x * 4 + (threadIdx.x >> 6);
    const int lane = threadIdx.x & 63;
    const float* zr = z + (size_t)row * DIM + lane * 16;
    float4 v[4];
    float ss = 0.f, am = 0.f;
#pragma unroll
    for (int j = 0; j < 4; ++j) {
        v[j] = *reinterpret_cast<const float4*>(zr + j * 4);
        ss += v[j].x * v[j].x + v[j].y * v[j].y + v[j].z * v[j].z + v[j].w * v[j].w;
        am = fmaxf(am, fmaxf(fmaxf(fabsf(v[j].x), fabsf(v[j].y)),
                             fmaxf(fabsf(v[j].z), fabsf(v[j].w))));
    }
#pragma unroll
    for (int m = 1; m < 64; m <<= 1) {
        ss += __shfl_xor(ss, m, 64);
        am = fmaxf(am, __shfl_xor(am, m, 64));
    }
    const float scale = 1.0f / fmaxf(sqrtf(ss), 1e-8f);
    const float amax  = am * scale;
    if (lane == 0) qs[row] = amax * (1.0f / 127.0f);
    const float f = (amax > 0.f) ? scale * (127.0f / amax) : 0.f;
    uint4 o;
    o.x = pk4(v[0], f);
    o.y = pk4(v[1], f);
    o.z = pk4(v[2], f);
    o.w = pk4(v[3], f);
    *reinterpret_cast<uint4*>(zq + (size_t)row * DIMB + lane * 16) = o;
}

// ---------------- Kernel 2: symmetric triangle int8 GEMM + dual partial LSE ----------------
// blocks 0..255  = 256 MINI 64x64 quarter-tiles of the last 16 triangle tiles
//                  (fill ALL 256 CUs for one short round -> balanced makespan)
// blocks 256..767 = 512 full 256x256 tiles (proven 2-phase structure).
__device__ __forceinline__ void stage_round(
    const signed char* __restrict__ zq, int g_row0, int k0,
    char* lds_round_base, int t) {
    const int r  = t >> 3;             // row within round (0..63)
    const int ch = (t & 7) ^ (r & 7);  // pre-swizzled 16B chunk (rule #21)
    const signed char* src = zq + (size_t)(g_row0 + r) * DIMB + k0 + ch * 16;
    __builtin_amdgcn_global_load_lds(
        (const __attribute__((address_space(1))) void*)src,
        (__attribute__((address_space(3))) void*)(lds_round_base + t * 16), 16, 0, 0);
}

__device__ __forceinline__ i32x4 ld_frag(const char* tile, int row, int kbyte, int xm) {
    return *reinterpret_cast<const i32x4*>(tile + row * 128 + (kbyte ^ xm));
}

#define MFMAI8(a, b, c) __builtin_amdgcn_mfma_i32_16x16x64_i8((a), (b), (c), 0, 0, 0)

// Half-row of quadrants: MH fixed, both NH: 4(mi) x 4(nf) x 2(k) = 32 MFMAs
template <int MH>
__device__ __forceinline__ void mfma_half(i32x4 (&acc)[8][4], const i32x4 (&af)[4][2],
                                          const i32x4 (&bf)[4][2]) {
#pragma unroll
    for (int mi = 0; mi < 4; ++mi)
#pragma unroll
        for (int nf = 0; nf < 4; ++nf)
#pragma unroll
            for (int k = 0; k < 2; ++k)
                acc[MH * 4 + mi][nf] = MFMAI8(af[mi][k], bf[nf][k], acc[MH * 4 + mi][nf]);
}

__global__ __launch_bounds__(512, 2) void cl_simlse8_kernel(
    const signed char* __restrict__ zq, const float* __restrict__ qs,
    float2* __restrict__ part,  // [128 chunks][8192 rows]
    float* __restrict__ pos) {  // [8192]
    extern __shared__ char smem[];  // 128 KB

    const int t    = threadIdx.x;
    const int lane = t & 63;
    const int wid  = t >> 6;   // 0..7
    const int l15  = lane & 15;
    const int xm   = (lane & 7) << 4;        // read-side swizzle mask ((row&7)<<4)
    const int kq16 = ((lane >> 4) & 3) * 16; // k sub-chunk byte offset
    const float invT = 1.0f / 0.07f;

    if (blockIdx.x >= 256) {
        // ================= FULL 256x256 tile path (triangle ids 0..511) =================
        const int wr = wid >> 2;  // 0..1 (M)
        const int wc = wid & 3;   // 0..3 (N)
        const int fb = blockIdx.x - 256;
        const int id2 = (fb & 7) * 64 + (fb >> 3);  // bijective XCD chunking
        int ri = 0, rem = id2;
        while (rem >= 32 - ri) { rem -= 32 - ri; ++ri; }
        const int ci = ri + rem;  // ri <= ci
        const int rbase = ri * BM;
        const int cbase = ci * BN;

        const i32x4 zero4 = {0, 0, 0, 0};
        i32x4 acc[8][4];
#pragma unroll
        for (int m = 0; m < 8; ++m)
#pragma unroll
            for (int n = 0; n < 4; ++n) acc[m][n] = zero4;

        i32x4 af[4][2];   // current A-half (overwritten between phases)
        i32x4 bf[4][2];   // all B (nh0+nh1)

        // ---- prologue: stage kt0 (8 rounds) + kt1 A0+B (6 rounds) ----
        {
            char* A0b = smem;
            char* B0b = smem + 32768;
            char* A1b = smem + 65536;
            char* B1b = smem + 98304;
            stage_round(zq, rbase + 0,   0, A0b + 0,     t);
            stage_round(zq, rbase + 64,  0, A0b + 8192,  t);
            stage_round(zq, rbase + 128, 0, A0b + 16384, t);
            stage_round(zq, rbase + 192, 0, A0b + 24576, t);
            stage_round(zq, cbase + 0,   0, B0b + 0,     t);
            stage_round(zq, cbase + 64,  0, B0b + 8192,  t);
            stage_round(zq, cbase + 128, 0, B0b + 16384, t);
            stage_round(zq, cbase + 192, 0, B0b + 24576, t);
            stage_round(zq, rbase + 0,   BKB, A1b + 0,     t);
            stage_round(zq, rbase + 64,  BKB, A1b + 8192,  t);
            stage_round(zq, cbase + 0,   BKB, B1b + 0,     t);
            stage_round(zq, cbase + 64,  BKB, B1b + 8192,  t);
            stage_round(zq, cbase + 128, BKB, B1b + 16384, t);
            stage_round(zq, cbase + 192, BKB, B1b + 24576, t);
            asm volatile("s_waitcnt vmcnt(6)" ::: "memory");  // kt0 landed; kt1 A0+B in flight
            __builtin_amdgcn_sched_barrier(0);
            __builtin_amdgcn_s_barrier();
        }

        // ---- main loop: 2 phases per K-tile ----
        for (int kt = 0; kt < NT; ++kt) {
            const int c = kt & 1;
            char* curA = smem + c * 65536;
            char* curB = curA + 32768;
            char* nxtA = smem + (c ^ 1) * 65536;
            const int k2 = (kt + 2) * BKB;

            // ---- phase A: read A-mh0 (8) + B both halves (8); stage A1(kt+1); MFMA mh0 ----
#pragma unroll
            for (int mi = 0; mi < 4; ++mi)
#pragma unroll
                for (int k = 0; k < 2; ++k)
                    af[mi][k] = ld_frag(curA, wr * 64 + mi * 16 + l15, k * 64 + kq16, xm);
#pragma unroll
            for (int nf = 0; nf < 4; ++nf)
#pragma unroll
                for (int k = 0; k < 2; ++k)
                    bf[nf][k] = ld_frag(curB, wc * 64 + (nf >> 1) * 32 + (nf & 1) * 16 + l15,
                                        k * 64 + kq16, xm);
            if (kt + 1 < NT) {  // A1(kt+1) into nxt (its region last read in kt-1 phB, done)
                stage_round(zq, rbase + 128, (kt + 1) * BKB, nxtA + 16384, t);
                stage_round(zq, rbase + 192, (kt + 1) * BKB, nxtA + 24576, t);
            }
            __builtin_amdgcn_s_barrier();
            asm volatile("s_waitcnt lgkmcnt(0)" ::: "memory");
            __builtin_amdgcn_sched_barrier(0);
            __builtin_amdgcn_s_setprio(1);
            mfma_half<0>(acc, af, bf);
            __builtin_amdgcn_s_setprio(0);
            __builtin_amdgcn_s_barrier();

            // ---- phase B: read A-mh1 (8, overwrite af); stage A0+B(kt+2); MFMA mh1; boundary ----
#pragma unroll
            for (int mi = 0; mi < 4; ++mi)
#pragma unroll
                for (int k = 0; k < 2; ++k)
                    af[mi][k] = ld_frag(curA, 128 + wr * 64 + mi * 16 + l15, k * 64 + kq16, xm);
            if (kt + 2 < NT) {  // curA0/curB reads completed at phase-A barrier
                stage_round(zq, rbase + 0,   k2, curA + 0,     t);
                stage_round(zq, rbase + 64,  k2, curA + 8192,  t);
                stage_round(zq, cbase + 0,   k2, curB + 0,     t);
                stage_round(zq, cbase + 64,  k2, curB + 8192,  t);
                stage_round(zq, cbase + 128, k2, curB + 16384, t);
                stage_round(zq, cbase + 192, k2, curB + 24576, t);
            }
            __builtin_amdgcn_s_barrier();
            asm volatile("s_waitcnt lgkmcnt(0)" ::: "memory");
            __builtin_amdgcn_sched_barrier(0);
            __builtin_amdgcn_s_setprio(1);
            mfma_half<1>(acc, af, bf);
            __builtin_amdgcn_s_setprio(0);
            if (kt < NT - 2) {
                asm volatile("s_waitcnt vmcnt(6)" ::: "memory");  // waits A1(kt+1), leaves own 6
                __builtin_amdgcn_sched_barrier(0);
            } else if (kt == NT - 2) {
                asm volatile("s_waitcnt vmcnt(0)" ::: "memory");  // drain tail
                __builtin_amdgcn_sched_barrier(0);
            }
            __builtin_amdgcn_s_barrier();
        }

        // ---- epilogue A: row partials (dequant: logit = acc * qs[r] * qs[c] / T) ----
        const int chunk = ci * 4 + wc;
        float qc[4];
#pragma unroll
        for (int nf = 0; nf < 4; ++nf)
            qc[nf] = qs[cbase + wc * 64 + (nf >> 1) * 32 + (nf & 1) * 16 + l15] * invT;
#pragma unroll
        for (int mh = 0; mh < 2; ++mh) {
#pragma unroll
            for (int mi = 0; mi < 4; ++mi) {
#pragma unroll
                for (int reg = 0; reg < 4; ++reg) {
                    const int grow = rbase + wr * 64 + mh * 128 + mi * 16 + (lane >> 4) * 4 + reg;
                    const int posj = (grow - 4096) & (N_ROWS - 1);
                    const float qr = qs[grow];
                    float vals[4];
                    float rmax = -3.4e38f;
#pragma unroll
                    for (int nf = 0; nf < 4; ++nf) {
                        const int gcol = cbase + wc * 64 + (nf >> 1) * 32 + (nf & 1) * 16 + l15;
                        float logit = (float)acc[mh * 4 + mi][nf][reg] * qr * qc[nf];
                        if (gcol == grow) logit = -9e15f * invT;  // diag mask
                        if (gcol == posj) {
                            pos[grow] = logit;   // involution: pair covered once, both sides
                            pos[gcol] = logit;
                        }
                        vals[nf] = logit;
                        rmax = fmaxf(rmax, logit);
                    }
#pragma unroll
                    for (int msk = 1; msk < 16; msk <<= 1)
                        rmax = fmaxf(rmax, __shfl_xor(rmax, msk, 64));
                    float s = 0.f;
#pragma unroll
                    for (int nf = 0; nf < 4; ++nf) s += __expf(vals[nf] - rmax);
#pragma unroll
                    for (int msk = 1; msk < 16; msk <<= 1) s += __shfl_xor(s, msk, 64);
                    if (l15 == 0) {
                        part[(size_t)chunk * N_ROWS + grow] = make_float2(rmax, s);
                    }
                }
            }
        }

        // ---- epilogue B: column partials (transpose rows) — off-diag only ----
        if (ri != ci) {
#pragma unroll
            for (int mh = 0; mh < 2; ++mh) {
                const int chunkT = ri * 4 + wr + mh * 2;
                float qrow[4][4];
#pragma unroll
                for (int mi = 0; mi < 4; ++mi)
#pragma unroll
                    for (int reg = 0; reg < 4; ++reg)
                        qrow[mi][reg] = qs[rbase + wr * 64 + mh * 128 + mi * 16 +
                                           (lane >> 4) * 4 + reg] * invT;
#pragma unroll
                for (int nf = 0; nf < 4; ++nf) {
                    const int gcol = cbase + wc * 64 + (nf >> 1) * 32 + (nf & 1) * 16 + l15;
                    const float qcg = qs[gcol];
                    float cmax = -3.4e38f;
#pragma unroll
                    for (int mi = 0; mi < 4; ++mi)
#pragma unroll
                        for (int reg = 0; reg < 4; ++reg)
                            cmax = fmaxf(cmax, (float)acc[mh * 4 + mi][nf][reg] *
                                                   qrow[mi][reg] * qcg);
                    cmax = fmaxf(cmax, __shfl_xor(cmax, 16, 64));
                    cmax = fmaxf(cmax, __shfl_xor(cmax, 32, 64));
                    float cs = 0.f;
#pragma unroll
                    for (int mi = 0; mi < 4; ++mi)
#pragma unroll
                        for (int reg = 0; reg < 4; ++reg)
                            cs += __expf((float)acc[mh * 4 + mi][nf][reg] *
                                             qrow[mi][reg] * qcg - cmax);
                    cs += __shfl_xor(cs, 16, 64);
                    cs += __shfl_xor(cs, 32, 64);
                    if (lane < 16) {
                        part[(size_t)chunkT * N_ROWS + gcol] = make_float2(cmax, cs);
                    }
                }
            }
        }
    } else {
        // ================= MINI path: 64x64 quarter-tiles (tiles 512..527, 4x4 each) =================
        const int mb   = blockIdx.x;       // 0..255, launched FIRST (fills all CUs)
        const int id2  = 512 + (mb >> 4);
        const int sub  = mb & 15;
        const int rq   = sub >> 2;         // row quarter 0..3
        const int cq   = sub & 3;          // col quarter 0..3
        int ri = 0, rem = id2;
        while (rem >= 32 - ri) { rem -= 32 - ri; ++ri; }
        const int ci = ri + rem;
        const int srow = ri * BM + rq * 64;  // this mini's 64 rows
        const int scol = ci * BN + cq * 64;  // this mini's 64 cols

        char* Ab0 = smem;            // 8 KB each
        char* Ab1 = smem + 8192;
        char* Bb0 = smem + 16384;
        char* Bb1 = smem + 24576;
        float2* colm = (float2*)(smem + 32768);  // [4 waves][64 cols]

        const i32x4 zero4 = {0, 0, 0, 0};
        i32x4 acc1[4];
#pragma unroll
        for (int n = 0; n < 4; ++n) acc1[n] = zero4;
        i32x4 a1[2], b1[4][2];

        // prologue: stage kt0 (A 1 round + B 1 round; 512 thr cover 64 rows each)
        stage_round(zq, srow, 0, Ab0, t);
        stage_round(zq, scol, 0, Bb0, t);
        asm volatile("s_waitcnt vmcnt(0)" ::: "memory");
        __builtin_amdgcn_sched_barrier(0);
        __builtin_amdgcn_s_barrier();

        // 2-buffer K loop; waves 0..3 compute 16 rows x 64 cols each, waves 4..7 stage only
        for (int kt = 0; kt < NT; ++kt) {
            char* curA = (kt & 1) ? Ab1 : Ab0;
            char* curB = (kt & 1) ? Bb1 : Bb0;
            char* nxtA = (kt & 1) ? Ab0 : Ab1;
            char* nxtB = (kt & 1) ? Bb0 : Bb1;
            if (kt + 1 < NT) {
                const int k1 = (kt + 1) * BKB;
                stage_round(zq, srow, k1, nxtA, t);
                stage_round(zq, scol, k1, nxtB, t);
            }
            if (wid < 4) {
#pragma unroll
                for (int k = 0; k < 2; ++k)
                    a1[k] = ld_frag(curA, wid * 16 + l15, k * 64 + kq16, xm);
#pragma unroll
                for (int nf = 0; nf < 4; ++nf)
#pragma unroll
                    for (int k = 0; k < 2; ++k)
                        b1[nf][k] = ld_frag(curB, nf * 16 + l15, k * 64 + kq16, xm);
            }
            asm volatile("s_waitcnt lgkmcnt(0)" ::: "memory");
            __builtin_amdgcn_sched_barrier(0);
            __builtin_amdgcn_s_setprio(1);
            if (wid < 4) {
#pragma unroll
                for (int nf = 0; nf < 4; ++nf)
#pragma unroll
                    for (int k = 0; k < 2; ++k)
                        acc1[nf] = MFMAI8(a1[k], b1[nf][k], acc1[nf]);
            }
            __builtin_amdgcn_s_setprio(0);
            asm volatile("s_waitcnt vmcnt(0)" ::: "memory");
            __builtin_amdgcn_sched_barrier(0);
            __builtin_amdgcn_s_barrier();
        }

        // ---- epilogue A: row partials (this mini's 64 rows over its 64-col chunk) ----
        if (wid < 4) {
            const int chunk = scol >> 6;
            float qc[4];
#pragma unroll
            for (int nf = 0; nf < 4; ++nf) qc[nf] = qs[scol + nf * 16 + l15] * invT;
#pragma unroll
            for (int reg = 0; reg < 4; ++reg) {
                const int grow = srow + wid * 16 + (lane >> 4) * 4 + reg;
                const int posj = (grow - 4096) & (N_ROWS - 1);
                const float qr = qs[grow];
                float vals[4];
                float rmax = -3.4e38f;
#pragma unroll
                for (int nf = 0; nf < 4; ++nf) {
                    const int gcol = scol + nf * 16 + l15;
                    float logit = (float)acc1[nf][reg] * qr * qc[nf];
                    if (gcol == grow) logit = -9e15f * invT;  // diag sub-blocks of diag tiles
                    if (gcol == posj) {
                        pos[grow] = logit;
                        pos[gcol] = logit;
                    }
                    vals[nf] = logit;
                    rmax = fmaxf(rmax, logit);
                }
#pragma unroll
                for (int msk = 1; msk < 16; msk <<= 1)
                    rmax = fmaxf(rmax, __shfl_xor(rmax, msk, 64));
                float sum = 0.f;
#pragma unroll
                for (int nf = 0; nf < 4; ++nf) sum += __expf(vals[nf] - rmax);
#pragma unroll
                for (int msk = 1; msk < 16; msk <<= 1) sum += __shfl_xor(sum, msk, 64);
                if (l15 == 0) {
                    part[(size_t)chunk * N_ROWS + grow] = make_float2(rmax, sum);
                }
            }
        }

        // ---- epilogue B: column partials (transpose rows) — off-diag tiles only ----
        // For diag tiles the mirrored mini (cq,rq) covers these entries via its row path.
        if (ri != ci) {
            if (wid < 4) {
                float qrow[4];
#pragma unroll
                for (int reg = 0; reg < 4; ++reg)
                    qrow[reg] = qs[srow + wid * 16 + (lane >> 4) * 4 + reg] * invT;
#pragma unroll
                for (int nf = 0; nf < 4; ++nf) {
                    const int gcol = scol + nf * 16 + l15;
                    const float qcg = qs[gcol];
                    float cmax = -3.4e38f;
#pragma unroll
                    for (int reg = 0; reg < 4; ++reg)
                        cmax = fmaxf(cmax, (float)acc1[nf][reg] * qrow[reg] * qcg);
                    cmax = fmaxf(cmax, __shfl_xor(cmax, 16, 64));
                    cmax = fmaxf(cmax, __shfl_xor(cmax, 32, 64));
                    float cs = 0.f;
#pragma unroll
                    for (int reg = 0; reg < 4; ++reg)
                        cs += __expf((float)acc1[nf][reg] * qrow[reg] * qcg - cmax);
                    cs += __shfl_xor(cs, 16, 64);
                    cs += __shfl_xor(cs, 32, 64);
                    if (lane < 16) {
                        colm[wid * 64 + nf * 16 + lane] = make_float2(cmax, cs);  // 16-row partial
                    }
                }
            }
            __syncthreads();
            if (t < 64) {  // merge the 4 waves' 16-row partials per column
                float2 p0 = colm[0 * 64 + t];
                float2 p1 = colm[1 * 64 + t];
                float2 p2 = colm[2 * 64 + t];
                float2 p3 = colm[3 * 64 + t];
                float M = fmaxf(fmaxf(p0.x, p1.x), fmaxf(p2.x, p3.x));
                float S = p0.y * __expf(p0.x - M) + p1.y * __expf(p1.x - M) +
                          p2.y * __expf(p2.x - M) + p3.y * __expf(p3.x - M);
                const int chunkT = srow >> 6;  // = ri*4 + rq
                part[(size_t)chunkT * N_ROWS + scol + t] = make_float2(M, S);
            }
        }
    }
}

// ---------------- Kernel 3: combine partials -> per-block nll sums ----------------
__global__ __launch_bounds__(256) void cl_combine_kernel(
    const float2* __restrict__ part, const float* __restrict__ pos,
    float* __restrict__ bsum) {
    const int r = blockIdx.x * 256 + threadIdx.x;
    float M = -3.4e38f;
#pragma unroll 8
    for (int c = 0; c < 128; ++c) M = fmaxf(M, part[(size_t)c * N_ROWS + r].x);
    float L = 0.f;
#pragma unroll 8
    for (int c = 0; c < 128; ++c) {
        const float2 p = part[(size_t)c * N_ROWS + r];
        L += p.y * __expf(p.x - M);
    }
    float nll = M + logf(L) - pos[r];
    __shared__ float red[4];
#pragma unroll
    for (int msk = 1; msk < 64; msk <<= 1) nll += __shfl_xor(nll, msk, 64);
    if ((threadIdx.x & 63) == 0) red[threadIdx.x >> 6] = nll;
    __syncthreads();
    if (threadIdx.x == 0) bsum[blockIdx.x] = red[0] + red[1] + red[2] + red[3];
}

// ---------------- Kernel 4: final mean ----------------
__global__ void cl_final_kernel(const float* __restrict__ bsum, float* __restrict__ out) {
    const int lane = threadIdx.x;
    float v = (lane < 32) ? bsum[lane] : 0.f;
#pragma unroll
    for (int msk = 1; msk < 64; msk <<= 1) v += __shfl_xor(v, msk, 64);
    if (lane == 0) out[0] = v * (1.0f / (float)N_ROWS);
}

extern "C" void kernel_launch(void* const* d_in, const int* in_sizes, int n_in,
                              void* d_out, int out_size, void* d_ws, size_t ws_size,
                              hipStream_t stream) {
    const float* z = (const float*)d_in[0];
    float* out = (float*)d_out;

    uint8_t* ws = (uint8_t*)d_ws;
    signed char* zq = (signed char*)ws;                        //  8 MB
    float2* part = (float2*)(ws + ((size_t)8 << 20));          //  8 MB
    float* pos   = (float*)(ws + ((size_t)16 << 20));          // 32 KB
    float* qs    = (float*)(ws + ((size_t)16 << 20) + 32768);  // 32 KB
    float* bsum  = (float*)(ws + ((size_t)16 << 20) + 65536);  // 128 B

    (void)hipFuncSetAttribute((const void*)cl_simlse8_kernel,
                              hipFuncAttributeMaxDynamicSharedMemorySize, 131072);

    cl_norm_kernel<<<N_ROWS / 4, 256, 0, stream>>>(z, zq, qs);
    cl_simlse8_kernel<<<768, 512, 131072, stream>>>(zq, qs, part, pos);  // 256 minis + 512 fulls
    cl_combine_kernel<<<N_ROWS / 256, 256, 0, stream>>>(part, pos, bsum);
    cl_final_kernel<<<1, 64, 0, stream>>>(bsum, out);
}

// Round 27
// 117.903 us; speedup vs baseline: 1.0233x; 1.0092x over previous
//
#include <hip/hip_runtime.h>
#include <hip/hip_bf16.h>
#include <math.h>

#define N_ROWS 8192
#define DIM 1024
#define DIMB 1024         // bytes per int8 row
#define BM 256
#define BN 256
#define BKB 128           // K-tile in BYTES (=128 int8 elems = 2 MFMA k-steps)
#define NT (DIMB / BKB)   // 8 K-tiles

typedef __attribute__((ext_vector_type(4))) int i32x4;

__device__ __forceinline__ unsigned pk4(float4 v, float f) {
    float c0 = fmaxf(-127.f, fminf(127.f, v.x * f));
    float c1 = fmaxf(-127.f, fminf(127.f, v.y * f));
    float c2 = fmaxf(-127.f, fminf(127.f, v.z * f));
    float c3 = fmaxf(-127.f, fminf(127.f, v.w * f));
    int b0 = (int)rintf(c0), b1 = (int)rintf(c1);
    int b2 = (int)rintf(c2), b3 = (int)rintf(c3);
    return (unsigned)(b0 & 0xFF) | ((unsigned)(b1 & 0xFF) << 8) |
           ((unsigned)(b2 & 0xFF) << 16) | ((unsigned)(b3 & 0xFF) << 24);
}

// ---------------- Kernel 1: row L2-normalize fp32 -> per-row-scaled int8 ----------------
__global__ __launch_bounds__(256) void cl_norm_kernel(
    const float* __restrict__ z, signed char* __restrict__ zq, float* __restrict__ qs) {
    const int row  = blockIdx.x * 4 + (threadIdx.x >> 6);
    const int lane = threadIdx.x & 63;
    const float* zr = z + (size_t)row * DIM + lane * 16;
    float4 v[4];
    float ss = 0.f, am = 0.f;
#pragma unroll
    for (int j = 0; j < 4; ++j) {
        v[j] = *reinterpret_cast<const float4*>(zr + j * 4);
        ss += v[j].x * v[j].x + v[j].y * v[j].y + v[j].z * v[j].z + v[j].w * v[j].w;
        am = fmaxf(am, fmaxf(fmaxf(fabsf(v[j].x), fabsf(v[j].y)),
                             fmaxf(fabsf(v[j].z), fabsf(v[j].w))));
    }
#pragma unroll
    for (int m = 1; m < 64; m <<= 1) {
        ss += __shfl_xor(ss, m, 64);
        am = fmaxf(am, __shfl_xor(am, m, 64));
    }
    const float scale = 1.0f / fmaxf(sqrtf(ss), 1e-8f);
    const float amax  = am * scale;
    if (lane == 0) qs[row] = amax * (1.0f / 127.0f);
    const float f = (amax > 0.f) ? scale * (127.0f / amax) : 0.f;
    uint4 o;
    o.x = pk4(v[0], f);
    o.y = pk4(v[1], f);
    o.z = pk4(v[2], f);
    o.w = pk4(v[3], f);
    *reinterpret_cast<uint4*>(zq + (size_t)row * DIMB + lane * 16) = o;
}

// ---------------- Kernel 2: symmetric triangle int8 GEMM + dual partial LSE ----------------
// blocks 0..255  = 256 MINI 64x64 quarter-tiles of the last 16 triangle tiles
//                  (now with 3-buffer 2-deep counted-vmcnt pipeline)
// blocks 256..767 = 512 full 256x256 tiles (proven 2-phase structure).
__device__ __forceinline__ void stage_round(
    const signed char* __restrict__ zq, int g_row0, int k0,
    char* lds_round_base, int t) {
    const int r  = t >> 3;             // row within round (0..63)
    const int ch = (t & 7) ^ (r & 7);  // pre-swizzled 16B chunk (rule #21)
    const signed char* src = zq + (size_t)(g_row0 + r) * DIMB + k0 + ch * 16;
    __builtin_amdgcn_global_load_lds(
        (const __attribute__((address_space(1))) void*)src,
        (__attribute__((address_space(3))) void*)(lds_round_base + t * 16), 16, 0, 0);
}

__device__ __forceinline__ i32x4 ld_frag(const char* tile, int row, int kbyte, int xm) {
    return *reinterpret_cast<const i32x4*>(tile + row * 128 + (kbyte ^ xm));
}

#define MFMAI8(a, b, c) __builtin_amdgcn_mfma_i32_16x16x64_i8((a), (b), (c), 0, 0, 0)

// Half-row of quadrants: MH fixed, both NH: 4(mi) x 4(nf) x 2(k) = 32 MFMAs
template <int MH>
__device__ __forceinline__ void mfma_half(i32x4 (&acc)[8][4], const i32x4 (&af)[4][2],
                                          const i32x4 (&bf)[4][2]) {
#pragma unroll
    for (int mi = 0; mi < 4; ++mi)
#pragma unroll
        for (int nf = 0; nf < 4; ++nf)
#pragma unroll
            for (int k = 0; k < 2; ++k)
                acc[MH * 4 + mi][nf] = MFMAI8(af[mi][k], bf[nf][k], acc[MH * 4 + mi][nf]);
}

__global__ __launch_bounds__(512, 2) void cl_simlse8_kernel(
    const signed char* __restrict__ zq, const float* __restrict__ qs,
    float2* __restrict__ part,  // [128 chunks][8192 rows]
    float* __restrict__ pos) {  // [8192]
    extern __shared__ char smem[];  // 128 KB

    const int t    = threadIdx.x;
    const int lane = t & 63;
    const int wid  = t >> 6;   // 0..7
    const int l15  = lane & 15;
    const int xm   = (lane & 7) << 4;        // read-side swizzle mask ((row&7)<<4)
    const int kq16 = ((lane >> 4) & 3) * 16; // k sub-chunk byte offset
    const float invT = 1.0f / 0.07f;

    if (blockIdx.x >= 256) {
        // ================= FULL 256x256 tile path (triangle ids 0..511) =================
        const int wr = wid >> 2;  // 0..1 (M)
        const int wc = wid & 3;   // 0..3 (N)
        const int fb = blockIdx.x - 256;
        const int id2 = (fb & 7) * 64 + (fb >> 3);  // bijective XCD chunking
        int ri = 0, rem = id2;
        while (rem >= 32 - ri) { rem -= 32 - ri; ++ri; }
        const int ci = ri + rem;  // ri <= ci
        const int rbase = ri * BM;
        const int cbase = ci * BN;

        const i32x4 zero4 = {0, 0, 0, 0};
        i32x4 acc[8][4];
#pragma unroll
        for (int m = 0; m < 8; ++m)
#pragma unroll
            for (int n = 0; n < 4; ++n) acc[m][n] = zero4;

        i32x4 af[4][2];   // current A-half (overwritten between phases)
        i32x4 bf[4][2];   // all B (nh0+nh1)

        // ---- prologue: stage kt0 (8 rounds) + kt1 A0+B (6 rounds) ----
        {
            char* A0b = smem;
            char* B0b = smem + 32768;
            char* A1b = smem + 65536;
            char* B1b = smem + 98304;
            stage_round(zq, rbase + 0,   0, A0b + 0,     t);
            stage_round(zq, rbase + 64,  0, A0b + 8192,  t);
            stage_round(zq, rbase + 128, 0, A0b + 16384, t);
            stage_round(zq, rbase + 192, 0, A0b + 24576, t);
            stage_round(zq, cbase + 0,   0, B0b + 0,     t);
            stage_round(zq, cbase + 64,  0, B0b + 8192,  t);
            stage_round(zq, cbase + 128, 0, B0b + 16384, t);
            stage_round(zq, cbase + 192, 0, B0b + 24576, t);
            stage_round(zq, rbase + 0,   BKB, A1b + 0,     t);
            stage_round(zq, rbase + 64,  BKB, A1b + 8192,  t);
            stage_round(zq, cbase + 0,   BKB, B1b + 0,     t);
            stage_round(zq, cbase + 64,  BKB, B1b + 8192,  t);
            stage_round(zq, cbase + 128, BKB, B1b + 16384, t);
            stage_round(zq, cbase + 192, BKB, B1b + 24576, t);
            asm volatile("s_waitcnt vmcnt(6)" ::: "memory");  // kt0 landed; kt1 A0+B in flight
            __builtin_amdgcn_sched_barrier(0);
            __builtin_amdgcn_s_barrier();
        }

        // ---- main loop: 2 phases per K-tile ----
        for (int kt = 0; kt < NT; ++kt) {
            const int c = kt & 1;
            char* curA = smem + c * 65536;
            char* curB = curA + 32768;
            char* nxtA = smem + (c ^ 1) * 65536;
            const int k2 = (kt + 2) * BKB;

            // ---- phase A: read A-mh0 (8) + B both halves (8); stage A1(kt+1); MFMA mh0 ----
#pragma unroll
            for (int mi = 0; mi < 4; ++mi)
#pragma unroll
                for (int k = 0; k < 2; ++k)
                    af[mi][k] = ld_frag(curA, wr * 64 + mi * 16 + l15, k * 64 + kq16, xm);
#pragma unroll
            for (int nf = 0; nf < 4; ++nf)
#pragma unroll
                for (int k = 0; k < 2; ++k)
                    bf[nf][k] = ld_frag(curB, wc * 64 + (nf >> 1) * 32 + (nf & 1) * 16 + l15,
                                        k * 64 + kq16, xm);
            if (kt + 1 < NT) {  // A1(kt+1) into nxt (its region last read in kt-1 phB, done)
                stage_round(zq, rbase + 128, (kt + 1) * BKB, nxtA + 16384, t);
                stage_round(zq, rbase + 192, (kt + 1) * BKB, nxtA + 24576, t);
            }
            __builtin_amdgcn_s_barrier();
            asm volatile("s_waitcnt lgkmcnt(0)" ::: "memory");
            __builtin_amdgcn_sched_barrier(0);
            __builtin_amdgcn_s_setprio(1);
            mfma_half<0>(acc, af, bf);
            __builtin_amdgcn_s_setprio(0);
            __builtin_amdgcn_s_barrier();

            // ---- phase B: read A-mh1 (8, overwrite af); stage A0+B(kt+2); MFMA mh1; boundary ----
#pragma unroll
            for (int mi = 0; mi < 4; ++mi)
#pragma unroll
                for (int k = 0; k < 2; ++k)
                    af[mi][k] = ld_frag(curA, 128 + wr * 64 + mi * 16 + l15, k * 64 + kq16, xm);
            if (kt + 2 < NT) {  // curA0/curB reads completed at phase-A barrier
                stage_round(zq, rbase + 0,   k2, curA + 0,     t);
                stage_round(zq, rbase + 64,  k2, curA + 8192,  t);
                stage_round(zq, cbase + 0,   k2, curB + 0,     t);
                stage_round(zq, cbase + 64,  k2, curB + 8192,  t);
                stage_round(zq, cbase + 128, k2, curB + 16384, t);
                stage_round(zq, cbase + 192, k2, curB + 24576, t);
            }
            __builtin_amdgcn_s_barrier();
            asm volatile("s_waitcnt lgkmcnt(0)" ::: "memory");
            __builtin_amdgcn_sched_barrier(0);
            __builtin_amdgcn_s_setprio(1);
            mfma_half<1>(acc, af, bf);
            __builtin_amdgcn_s_setprio(0);
            if (kt < NT - 2) {
                asm volatile("s_waitcnt vmcnt(6)" ::: "memory");  // waits A1(kt+1), leaves own 6
                __builtin_amdgcn_sched_barrier(0);
            } else if (kt == NT - 2) {
                asm volatile("s_waitcnt vmcnt(0)" ::: "memory");  // drain tail
                __builtin_amdgcn_sched_barrier(0);
            }
            __builtin_amdgcn_s_barrier();
        }

        // ---- epilogue A: row partials (dequant: logit = acc * qs[r] * qs[c] / T) ----
        const int chunk = ci * 4 + wc;
        float qc[4];
#pragma unroll
        for (int nf = 0; nf < 4; ++nf)
            qc[nf] = qs[cbase + wc * 64 + (nf >> 1) * 32 + (nf & 1) * 16 + l15] * invT;
#pragma unroll
        for (int mh = 0; mh < 2; ++mh) {
#pragma unroll
            for (int mi = 0; mi < 4; ++mi) {
#pragma unroll
                for (int reg = 0; reg < 4; ++reg) {
                    const int grow = rbase + wr * 64 + mh * 128 + mi * 16 + (lane >> 4) * 4 + reg;
                    const int posj = (grow - 4096) & (N_ROWS - 1);
                    const float qr = qs[grow];
                    float vals[4];
                    float rmax = -3.4e38f;
#pragma unroll
                    for (int nf = 0; nf < 4; ++nf) {
                        const int gcol = cbase + wc * 64 + (nf >> 1) * 32 + (nf & 1) * 16 + l15;
                        float logit = (float)acc[mh * 4 + mi][nf][reg] * qr * qc[nf];
                        if (gcol == grow) logit = -9e15f * invT;  // diag mask
                        if (gcol == posj) {
                            pos[grow] = logit;   // involution: pair covered once, both sides
                            pos[gcol] = logit;
                        }
                        vals[nf] = logit;
                        rmax = fmaxf(rmax, logit);
                    }
#pragma unroll
                    for (int msk = 1; msk < 16; msk <<= 1)
                        rmax = fmaxf(rmax, __shfl_xor(rmax, msk, 64));
                    float s = 0.f;
#pragma unroll
                    for (int nf = 0; nf < 4; ++nf) s += __expf(vals[nf] - rmax);
#pragma unroll
                    for (int msk = 1; msk < 16; msk <<= 1) s += __shfl_xor(s, msk, 64);
                    if (l15 == 0) {
                        part[(size_t)chunk * N_ROWS + grow] = make_float2(rmax, s);
                    }
                }
            }
        }

        // ---- epilogue B: column partials (transpose rows) — off-diag only ----
        if (ri != ci) {
#pragma unroll
            for (int mh = 0; mh < 2; ++mh) {
                const int chunkT = ri * 4 + wr + mh * 2;
                float qrow[4][4];
#pragma unroll
                for (int mi = 0; mi < 4; ++mi)
#pragma unroll
                    for (int reg = 0; reg < 4; ++reg)
                        qrow[mi][reg] = qs[rbase + wr * 64 + mh * 128 + mi * 16 +
                                           (lane >> 4) * 4 + reg] * invT;
#pragma unroll
                for (int nf = 0; nf < 4; ++nf) {
                    const int gcol = cbase + wc * 64 + (nf >> 1) * 32 + (nf & 1) * 16 + l15;
                    const float qcg = qs[gcol];
                    float cmax = -3.4e38f;
#pragma unroll
                    for (int mi = 0; mi < 4; ++mi)
#pragma unroll
                        for (int reg = 0; reg < 4; ++reg)
                            cmax = fmaxf(cmax, (float)acc[mh * 4 + mi][nf][reg] *
                                                   qrow[mi][reg] * qcg);
                    cmax = fmaxf(cmax, __shfl_xor(cmax, 16, 64));
                    cmax = fmaxf(cmax, __shfl_xor(cmax, 32, 64));
                    float cs = 0.f;
#pragma unroll
                    for (int mi = 0; mi < 4; ++mi)
#pragma unroll
                        for (int reg = 0; reg < 4; ++reg)
                            cs += __expf((float)acc[mh * 4 + mi][nf][reg] *
                                             qrow[mi][reg] * qcg - cmax);
                    cs += __shfl_xor(cs, 16, 64);
                    cs += __shfl_xor(cs, 32, 64);
                    if (lane < 16) {
                        part[(size_t)chunkT * N_ROWS + gcol] = make_float2(cmax, cs);
                    }
                }
            }
        }
    } else {
        // ================= MINI path: 64x64 quarter-tiles, 3-buffer counted-vmcnt pipeline =================
        const int mb   = blockIdx.x;       // 0..255, launched FIRST (fills all CUs)
        const int id2  = 512 + (mb >> 4);
        const int sub  = mb & 15;
        const int rq   = sub >> 2;         // row quarter 0..3
        const int cq   = sub & 3;          // col quarter 0..3
        int ri = 0, rem = id2;
        while (rem >= 32 - ri) { rem -= 32 - ri; ++ri; }
        const int ci = ri + rem;
        const int srow = ri * BM + rq * 64;  // this mini's 64 rows
        const int scol = ci * BN + cq * 64;  // this mini's 64 cols

        char* Ab[3] = { smem,          smem + 8192,  smem + 16384 };
        char* Bb[3] = { smem + 24576,  smem + 32768, smem + 40960 };
        float2* colm = (float2*)(smem + 49152);  // [4 waves][64 cols], 2 KB

        const i32x4 zero4 = {0, 0, 0, 0};
        i32x4 acc1[4];
#pragma unroll
        for (int n = 0; n < 4; ++n) acc1[n] = zero4;
        i32x4 a1[2], b1[4][2];

        // prologue: stage kt0 + kt1 (4 issues); wait kt0 landed (kt1 in flight)
        stage_round(zq, srow, 0,   Ab[0], t);
        stage_round(zq, scol, 0,   Bb[0], t);
        stage_round(zq, srow, BKB, Ab[1], t);
        stage_round(zq, scol, BKB, Bb[1], t);
        asm volatile("s_waitcnt vmcnt(2)" ::: "memory");
        __builtin_amdgcn_sched_barrier(0);
        __builtin_amdgcn_s_barrier();

        // 3-buffer K loop, 2-deep prefetch, counted vmcnt(2) boundary.
        // WAR: buf[(kt+2)%3] last ds_read in loop kt-1, drained at its lgkmcnt(0)
        // before its ending barrier; stage issued after that barrier -> safe.
        for (int kt = 0; kt < NT; ++kt) {
            char* curA = Ab[kt % 3];
            char* curB = Bb[kt % 3];
            if (kt + 2 < NT) {
                const int k2 = (kt + 2) * BKB;
                stage_round(zq, srow, k2, Ab[(kt + 2) % 3], t);
                stage_round(zq, scol, k2, Bb[(kt + 2) % 3], t);
            }
            if (wid < 4) {
#pragma unroll
                for (int k = 0; k < 2; ++k)
                    a1[k] = ld_frag(curA, wid * 16 + l15, k * 64 + kq16, xm);
#pragma unroll
                for (int nf = 0; nf < 4; ++nf)
#pragma unroll
                    for (int k = 0; k < 2; ++k)
                        b1[nf][k] = ld_frag(curB, nf * 16 + l15, k * 64 + kq16, xm);
            }
            asm volatile("s_waitcnt lgkmcnt(0)" ::: "memory");
            __builtin_amdgcn_sched_barrier(0);
            __builtin_amdgcn_s_setprio(1);
            if (wid < 4) {
#pragma unroll
                for (int nf = 0; nf < 4; ++nf)
#pragma unroll
                    for (int k = 0; k < 2; ++k)
                        acc1[nf] = MFMAI8(a1[k], b1[nf][k], acc1[nf]);
            }
            __builtin_amdgcn_s_setprio(0);
            if (kt < NT - 2) {
                asm volatile("s_waitcnt vmcnt(2)" ::: "memory");  // kt+1 landed; kt+2 in flight
                __builtin_amdgcn_sched_barrier(0);
            } else if (kt == NT - 2) {
                asm volatile("s_waitcnt vmcnt(0)" ::: "memory");  // drain tail
                __builtin_amdgcn_sched_barrier(0);
            }
            __builtin_amdgcn_s_barrier();
        }

        // ---- epilogue A: row partials (this mini's 64 rows over its 64-col chunk) ----
        if (wid < 4) {
            const int chunk = scol >> 6;
            float qc[4];
#pragma unroll
            for (int nf = 0; nf < 4; ++nf) qc[nf] = qs[scol + nf * 16 + l15] * invT;
#pragma unroll
            for (int reg = 0; reg < 4; ++reg) {
                const int grow = srow + wid * 16 + (lane >> 4) * 4 + reg;
                const int posj = (grow - 4096) & (N_ROWS - 1);
                const float qr = qs[grow];
                float vals[4];
                float rmax = -3.4e38f;
#pragma unroll
                for (int nf = 0; nf < 4; ++nf) {
                    const int gcol = scol + nf * 16 + l15;
                    float logit = (float)acc1[nf][reg] * qr * qc[nf];
                    if (gcol == grow) logit = -9e15f * invT;  // diag sub-blocks of diag tiles
                    if (gcol == posj) {
                        pos[grow] = logit;
                        pos[gcol] = logit;
                    }
                    vals[nf] = logit;
                    rmax = fmaxf(rmax, logit);
                }
#pragma unroll
                for (int msk = 1; msk < 16; msk <<= 1)
                    rmax = fmaxf(rmax, __shfl_xor(rmax, msk, 64));
                float sum = 0.f;
#pragma unroll
                for (int nf = 0; nf < 4; ++nf) sum += __expf(vals[nf] - rmax);
#pragma unroll
                for (int msk = 1; msk < 16; msk <<= 1) sum += __shfl_xor(sum, msk, 64);
                if (l15 == 0) {
                    part[(size_t)chunk * N_ROWS + grow] = make_float2(rmax, sum);
                }
            }
        }

        // ---- epilogue B: column partials (transpose rows) — off-diag tiles only ----
        // For diag tiles the mirrored mini (cq,rq) covers these entries via its row path.
        if (ri != ci) {
            if (wid < 4) {
                float qrow[4];
#pragma unroll
                for (int reg = 0; reg < 4; ++reg)
                    qrow[reg] = qs[srow + wid * 16 + (lane >> 4) * 4 + reg] * invT;
#pragma unroll
                for (int nf = 0; nf < 4; ++nf) {
                    const int gcol = scol + nf * 16 + l15;
                    const float qcg = qs[gcol];
                    float cmax = -3.4e38f;
#pragma unroll
                    for (int reg = 0; reg < 4; ++reg)
                        cmax = fmaxf(cmax, (float)acc1[nf][reg] * qrow[reg] * qcg);
                    cmax = fmaxf(cmax, __shfl_xor(cmax, 16, 64));
                    cmax = fmaxf(cmax, __shfl_xor(cmax, 32, 64));
                    float cs = 0.f;
#pragma unroll
                    for (int reg = 0; reg < 4; ++reg)
                        cs += __expf((float)acc1[nf][reg] * qrow[reg] * qcg - cmax);
                    cs += __shfl_xor(cs, 16, 64);
                    cs += __shfl_xor(cs, 32, 64);
                    if (lane < 16) {
                        colm[wid * 64 + nf * 16 + lane] = make_float2(cmax, cs);  // 16-row partial
                    }
                }
            }
            __syncthreads();
            if (t < 64) {  // merge the 4 waves' 16-row partials per column
                float2 p0 = colm[0 * 64 + t];
                float2 p1 = colm[1 * 64 + t];
                float2 p2 = colm[2 * 64 + t];
                float2 p3 = colm[3 * 64 + t];
                float M = fmaxf(fmaxf(p0.x, p1.x), fmaxf(p2.x, p3.x));
                float S = p0.y * __expf(p0.x - M) + p1.y * __expf(p1.x - M) +
                          p2.y * __expf(p2.x - M) + p3.y * __expf(p3.x - M);
                const int chunkT = srow >> 6;  // = ri*4 + rq
                part[(size_t)chunkT * N_ROWS + scol + t] = make_float2(M, S);
            }
        }
    }
}

// ---------------- Kernel 3: combine partials -> per-block nll sums ----------------
__global__ __launch_bounds__(256) void cl_combine_kernel(
    const float2* __restrict__ part, const float* __restrict__ pos,
    float* __restrict__ bsum) {
    const int r = blockIdx.x * 256 + threadIdx.x;
    float M = -3.4e38f;
#pragma unroll 8
    for (int c = 0; c < 128; ++c) M = fmaxf(M, part[(size_t)c * N_ROWS + r].x);
    float L = 0.f;
#pragma unroll 8
    for (int c = 0; c < 128; ++c) {
        const float2 p = part[(size_t)c * N_ROWS + r];
        L += p.y * __expf(p.x - M);
    }
    float nll = M + logf(L) - pos[r];
    __shared__ float red[4];
#pragma unroll
    for (int msk = 1; msk < 64; msk <<= 1) nll += __shfl_xor(nll, msk, 64);
    if ((threadIdx.x & 63) == 0) red[threadIdx.x >> 6] = nll;
    __syncthreads();
    if (threadIdx.x == 0) bsum[blockIdx.x] = red[0] + red[1] + red[2] + red[3];
}

// ---------------- Kernel 4: final mean ----------------
__global__ void cl_final_kernel(const float* __restrict__ bsum, float* __restrict__ out) {
    const int lane = threadIdx.x;
    float v = (lane < 32) ? bsum[lane] : 0.f;
#pragma unroll
    for (int msk = 1; msk < 64; msk <<= 1) v += __shfl_xor(v, msk, 64);
    if (lane == 0) out[0] = v * (1.0f / (float)N_ROWS);
}

extern "C" void kernel_launch(void* const* d_in, const int* in_sizes, int n_in,
                              void* d_out, int out_size, void* d_ws, size_t ws_size,
                              hipStream_t stream) {
    const float* z = (const float*)d_in[0];
    float* out = (float*)d_out;

    uint8_t* ws = (uint8_t*)d_ws;
    signed char* zq = (signed char*)ws;                        //  8 MB
    float2* part = (float2*)(ws + ((size_t)8 << 20));          //  8 MB
    float* pos   = (float*)(ws + ((size_t)16 << 20));          // 32 KB
    float* qs    = (float*)(ws + ((size_t)16 << 20) + 32768);  // 32 KB
    float* bsum  = (float*)(ws + ((size_t)16 << 20) + 65536);  // 128 B

    (void)hipFuncSetAttribute((const void*)cl_simlse8_kernel,
                              hipFuncAttributeMaxDynamicSharedMemorySize, 131072);

    cl_norm_kernel<<<N_ROWS / 4, 256, 0, stream>>>(z, zq, qs);
    cl_simlse8_kernel<<<768, 512, 131072, stream>>>(zq, qs, part, pos);  // 256 minis + 512 fulls
    cl_combine_kernel<<<N_ROWS / 256, 256, 0, stream>>>(part, pos, bsum);
    cl_final_kernel<<<1, 64, 0, stream>>>(bsum, out);
}